// Round 13
// baseline (331.245 us; speedup 1.0000x reference)
//
#include <hip/hip_runtime.h>
#include <cstdint>

// LatentFactorPooling on MI355X.
// x: (64,256,64,44) fp32, basis: (4,16,256) fp32.
// out: tokens (64,256,64) fp32 then pres (64,64) fp32.
//
// Round-16: tokens GEMM FUSED into k_route as pass 2. Rationale: k_tokens
// was pinned at ~100us by a ~63us DS-pipe floor (supp broadcast reads) +
// overheads; occupancy changes were neutral (r11, r12). Fusion deletes the
// supp 11.5MB write + 23MB re-read, the partials round-trip, k_tok_red, and
// two launches; x for pass 2 is L2/L3-warm from pass 1. Pass 1 and the
// epilogue math are bit-identical to the proven round-9 monolith.
//
// Workspace layout (floats):
//   lbn_ws     [0,16384)             normalized basis, [g][c][k]
//   presraw    [20480,24576)         unnormalized presence per (s,k)

#define C_ 256
#define W_ 44
#define P_ 704          // 16*44 positions per stripe
#define CH_STRIDE 2816  // 64*44
#define NB_STRIDE 720896 // 256*2816
#define TOPK_ 88
#define GATE_ 0.05f
#define EPS_ 1e-6f

// DPP wave-wide shifts: lane i <- lane i-1 (shr) / i+1 (shl), bound_ctrl
// zero-fills the edge lane. VALU pipe.
#define DPP_WAVE_SHL1 0x130
#define DPP_WAVE_SHR1 0x138
__device__ __forceinline__ float dpp_from_left(float v) {   // lane l gets v[l-1], lane0 -> 0
  return __int_as_float(__builtin_amdgcn_update_dpp(
      0, __float_as_int(v), DPP_WAVE_SHR1, 0xF, 0xF, true));
}
__device__ __forceinline__ float dpp_from_right(float v) {  // lane l gets v[l+1], lane63 -> 0
  return __int_as_float(__builtin_amdgcn_update_dpp(
      0, __float_as_int(v), DPP_WAVE_SHL1, 0xF, 0xF, true));
}

// ---------------- kernel A: normalize latent basis ----------------
__global__ __launch_bounds__(256) void k_norm_basis(const float* __restrict__ lb,
                                                    float* __restrict__ lbn) {
  int gk = blockIdx.x;           // g*16+k
  int t = threadIdx.x;           // channel
  float v = lb[gk * 256 + t];
  float ss = v * v;
  #pragma unroll
  for (int off = 32; off >= 1; off >>= 1) ss += __shfl_xor(ss, off);
  __shared__ float red[4];
  if ((t & 63) == 0) red[t >> 6] = ss;
  __syncthreads();
  float tot = red[0] + red[1] + red[2] + red[3];
  float scale = 1.f / fmaxf(sqrtf(tot), 1e-12f);
  int g = gk >> 4, k = gk & 15;
  lbn[((g * 256 + t) << 4) + k] = v * scale;   // [g][c][k]
}

// ---------------- kernel B: MONOLITH routing + fused tokens ----------------
// One block per stripe, 1024 threads.
// Pass 1 (wave = stripe row, lanes 0..43 active): rawdot/sq/pw2, barrier-free,
// LDS-free (DPP horizontal exchange, basis via wave-uniform scalar loads).
// Epilogue: 3x3 pool via LDS, energy gate, softmax -> supp, invden (LDS).
// Pass 2 (thread = (channel, pos-quarter)): tokens GEMM out[c][k] =
// invden[k] * sum_p x[c][p]*supp[p][k], supp from LDS broadcast, x staged
// through LDS in 44 16-position tiles. Then fused exact top-88 radix select.
#define LOAD_GRP(Pm, P0, Pp, cbase)                                    \
  { _Pragma("unroll")                                                  \
    for (int j_ = 0; j_ < 4; j_++) {                                   \
      const size_t o_ = (size_t)((cbase) + j_) * CH_STRIDE;            \
      Pm[j_] = xm[o_]; P0[j_] = xb[o_]; Pp[j_] = xp[o_];               \
    } }

#define CONS_GRP(Pm, P0, Pp, cbase)                                    \
  { _Pragma("unroll")                                                  \
    for (int j_ = 0; j_ < 4; j_++) {                                   \
      float a  = act ? P0[j_] : 0.f;                                   \
      float am_ = (act && hm) ? Pm[j_] : 0.f;                          \
      float ap_ = (act && hp) ? Pp[j_] : 0.f;                          \
      float vs = am_ + a + ap_;                                        \
      float lf = dpp_from_left(vs);                                    \
      float rt = dpp_from_right(vs);                                   \
      float win = lf + vs + rt;                                        \
      pw2 = fmaf(win, win, pw2);                                       \
      sq  = fmaf(a, a, sq);                                            \
      const int co_ = __builtin_amdgcn_readfirstlane(((cbase) + j_) << 4); \
      const float4* wp4 = (const float4*)(lbb + co_);                  \
      float4 w0 = wp4[0], w1 = wp4[1], w2 = wp4[2], w3 = wp4[3];       \
      rawdot[0]  = fmaf(a, w0.x, rawdot[0]);  rawdot[1]  = fmaf(a, w0.y, rawdot[1]);  \
      rawdot[2]  = fmaf(a, w0.z, rawdot[2]);  rawdot[3]  = fmaf(a, w0.w, rawdot[3]);  \
      rawdot[4]  = fmaf(a, w1.x, rawdot[4]);  rawdot[5]  = fmaf(a, w1.y, rawdot[5]);  \
      rawdot[6]  = fmaf(a, w1.z, rawdot[6]);  rawdot[7]  = fmaf(a, w1.w, rawdot[7]);  \
      rawdot[8]  = fmaf(a, w2.x, rawdot[8]);  rawdot[9]  = fmaf(a, w2.y, rawdot[9]);  \
      rawdot[10] = fmaf(a, w2.z, rawdot[10]); rawdot[11] = fmaf(a, w2.w, rawdot[11]); \
      rawdot[12] = fmaf(a, w3.x, rawdot[12]); rawdot[13] = fmaf(a, w3.y, rawdot[13]); \
      rawdot[14] = fmaf(a, w3.z, rawdot[14]); rawdot[15] = fmaf(a, w3.w, rawdot[15]); \
    } }

__global__ __launch_bounds__(1024, 1) void k_route(const float* __restrict__ x,
                                                   const float* __restrict__ lbn,
                                                   float* __restrict__ out,
                                                   float* __restrict__ presraw) {
  __shared__ float rsl[11264];          // rawdot [k][704], then supp [k][704]; 44 KB
  __shared__ float sl2[11264];          // supp [p][k]; reused for quarter-reduce; 44 KB
  __shared__ uint32_t scratch16[4096];  // pass2: x tile [256c][16p]; topk: histograms; 16 KB
  __shared__ float redA[16];
  __shared__ float redB[16];
  __shared__ float redM[2];
  __shared__ float red2[16 * 16];
  __shared__ float invden_l[16];

  float* xl2f = (float*)scratch16;

  const int tid = threadIdx.x;
  const int w = tid >> 6;          // row
  const int l = tid & 63;          // col
  const bool act = (l < 44);
  const int s = blockIdx.x, n = s >> 2, g = s & 3;
  const int p = w * 44 + l;

  const int lsafe = act ? l : 0;   // address clamp
  const float* xb = x + (size_t)n * NB_STRIDE + (g * 16 + w) * 44 + lsafe;
  const float* xm = xb + ((w > 0)  ? -44 : 0);   // clamped row addresses
  const float* xp = xb + ((w < 15) ?  44 : 0);
  const bool hm = (w > 0), hp = (w < 15);

  // wave-uniform basis base for this group: 256ch x 16k slice
  const float* lbb = lbn + (g << 12);

  float rawdot[16];
  #pragma unroll
  for (int k = 0; k < 16; k++) rawdot[k] = 0.f;
  float sq = 0.f, pw2 = 0.f;

  float Avm[4], Av0[4], Avp[4];
  float Bvm[4], Bv0[4], Bvp[4];

  LOAD_GRP(Avm, Av0, Avp, 0)
  for (int c = 0; c < 256; c += 8) {
    LOAD_GRP(Bvm, Bv0, Bvp, c + 4)
    CONS_GRP(Avm, Av0, Avp, c)
    if (c + 8 < 256) { LOAD_GRP(Avm, Av0, Avp, c + 8) }
    CONS_GRP(Bvm, Bv0, Bvp, c + 4)
  }

  // ---- epilogue: pool, gate, softmax, supp, invden ----
  if (act) {
    #pragma unroll
    for (int k = 0; k < 16; k++) rsl[k * 704 + p] = rawdot[k];
  }
  __syncthreads();   // rsl ready

  // 3x3 pool of rawdot (linearity: pool(raw).basis == pool(raw.basis))
  float pd[16];
  #pragma unroll
  for (int k = 0; k < 16; k++) pd[k] = 0.f;
  if (act) {
    #pragma unroll
    for (int dy = -1; dy <= 1; dy++) {
      int yy = w + dy;
      if (yy < 0 || yy > 15) continue;
      #pragma unroll
      for (int dx = -1; dx <= 1; dx++) {
        int xx = l + dx;
        if (xx < 0 || xx > 43) continue;
        int pp = yy * 44 + xx;
        #pragma unroll
        for (int k = 0; k < 16; k++) pd[k] += rsl[k * 704 + pp];
      }
    }
  }

  // stripe-wide energy max
  float e_raw = sq * (1.f / 256.f);            // inactive lanes: 0
  float m = e_raw;
  #pragma unroll
  for (int off = 32; off >= 1; off >>= 1) m = fmaxf(m, __shfl_xor(m, off));
  if (l == 0) redA[w] = m;
  __syncthreads();                             // (also: all rsl pool-reads done)
  if (tid == 0) {
    float mm = redA[0];
    for (int w2 = 1; w2 < 16; w2++) mm = fmaxf(mm, redA[w2]);
    redM[0] = mm;
  }
  __syncthreads();
  float M = fmaxf(redM[0], EPS_);
  float e = e_raw / M;
  float am = (e > GATE_) ? 1.f : 0.f;
  float fb = (e_raw > 0.f) ? 1.f : 0.f;
  float a = am;
  #pragma unroll
  for (int off = 32; off >= 1; off >>= 1) a += __shfl_xor(a, off);
  if (l == 0) redB[w] = a;
  __syncthreads();
  if (tid == 0) {
    float sm = 0.f;
    for (int w2 = 0; w2 < 16; w2++) sm += redB[w2];
    redM[1] = sm;
  }
  __syncthreads();
  if (redM[1] <= 0.f) am = fb;

  float pnorm = sqrtf(pw2) * (1.f / 9.f);      // ||pooled||
  float invn = 1.f / fmaxf(pnorm, 1e-12f);
  float scl = invn * (8.f / 9.f);              // /9 pool, /0.125 temp
  float li[16];
  float mx = -1e30f;
  #pragma unroll
  for (int k = 0; k < 16; k++) { li[k] = pd[k] * scl; mx = fmaxf(mx, li[k]); }
  float ssum = 0.f;
  #pragma unroll
  for (int k = 0; k < 16; k++) { li[k] = __expf(li[k] - mx); ssum += li[k]; }
  float rs2 = am / ssum;
  float supp[16];
  #pragma unroll
  for (int k = 0; k < 16; k++) supp[k] = li[k] * rs2;

  // supp -> LDS in BOTH layouts: rsl [k][704] (topk), sl2 [p][k] (pass 2).
  // (pool reads of rsl completed before the redA barrier above)
  if (act) {
    #pragma unroll
    for (int k = 0; k < 16; k++) rsl[k * 704 + p] = supp[k];
    float* spk = &sl2[p * 16];
    #pragma unroll
    for (int kq = 0; kq < 4; kq++)
      ((float4*)spk)[kq] = make_float4(supp[kq*4+0], supp[kq*4+1],
                                       supp[kq*4+2], supp[kq*4+3]);
  }

  // per-k denominators -> invden_l (inactive lanes contribute 0)
  #pragma unroll
  for (int k = 0; k < 16; k++) {
    float v2 = act ? supp[k] : 0.f;
    #pragma unroll
    for (int off = 32; off >= 1; off >>= 1) v2 += __shfl_xor(v2, off);
    if (l == 0) red2[w * 16 + k] = v2;
  }
  __syncthreads();   // red2 + rsl/sl2 supp visible
  if (tid < 16) {
    float den = 0.f;
    for (int w2 = 0; w2 < 16; w2++) den += red2[w2 * 16 + tid];
    invden_l[tid] = 1.f / fmaxf(den, EPS_);
  }
  __syncthreads();   // invden_l ready; sl2 ready

  // ---- PASS 2: tokens GEMM ----
  // thread = (channel cl2 = tid&255, quarter q2 = tid>>8). 44 tiles of 16
  // positions: stage x [256c][16p] into xl2f (swizzled float4 slots), read
  // supp[p][k] as uniform LDS broadcast, accumulate acc2[16].
  {
    const int sc = tid >> 2;            // staging channel
    const int sj = tid & 3;             // staging float4 slot
    const float* gps = x + (size_t)n * NB_STRIDE + (size_t)sc * CH_STRIDE
                         + g * 704 + sj * 4;
    const int wos = sc * 16 + ((sj ^ (sc & 3)) << 2);
    const int cl2 = tid & 255;          // compute channel
    const int q2 = tid >> 8;            // position quarter (wave-uniform)
    const int rdo = cl2 * 16 + (((q2 ^ (cl2 & 3))) << 2);

    float acc2[16];
    #pragma unroll
    for (int k = 0; k < 16; k++) acc2[k] = 0.f;

    for (int tt = 0; tt < 44; tt++) {
      float4 r = *(const float4*)(gps + tt * 16);
      __syncthreads();                  // previous tile's readers done
      *(float4*)&xl2f[wos] = r;
      __syncthreads();                  // tile visible
      float4 xv = *(const float4*)&xl2f[rdo];
      float xa[4] = {xv.x, xv.y, xv.z, xv.w};
      const int pbase = (tt * 16 + q2 * 4) * 16;
      #pragma unroll
      for (int dj = 0; dj < 4; dj++) {
        const float4* sp = (const float4*)&sl2[pbase + dj * 16];
        float4 s0 = sp[0], s1 = sp[1], s2 = sp[2], s3 = sp[3];
        float av = xa[dj];
        acc2[0]  += av * s0.x; acc2[1]  += av * s0.y; acc2[2]  += av * s0.z; acc2[3]  += av * s0.w;
        acc2[4]  += av * s1.x; acc2[5]  += av * s1.y; acc2[6]  += av * s1.z; acc2[7]  += av * s1.w;
        acc2[8]  += av * s2.x; acc2[9]  += av * s2.y; acc2[10] += av * s2.z; acc2[11] += av * s2.w;
        acc2[12] += av * s3.x; acc2[13] += av * s3.y; acc2[14] += av * s3.z; acc2[15] += av * s3.w;
      }
    }
    __syncthreads();   // last tile's supp/x reads done; sl2 free for reduce

    // quarter-reduce via sl2 (8192 of 11264 floats used)
    if (q2 >= 2) {
      float* dst = &sl2[((q2 - 2) * 256 + cl2) * 16];
      #pragma unroll
      for (int kq = 0; kq < 4; kq++)
        ((float4*)dst)[kq] = make_float4(acc2[kq*4], acc2[kq*4+1],
                                         acc2[kq*4+2], acc2[kq*4+3]);
    }
    __syncthreads();
    if (q2 < 2) {
      const float* src = &sl2[(q2 * 256 + cl2) * 16];
      #pragma unroll
      for (int k = 0; k < 16; k++) acc2[k] += src[k];
    }
    __syncthreads();
    if (q2 == 1) {
      float* dst = &sl2[cl2 * 16];
      #pragma unroll
      for (int kq = 0; kq < 4; kq++)
        ((float4*)dst)[kq] = make_float4(acc2[kq*4], acc2[kq*4+1],
                                         acc2[kq*4+2], acc2[kq*4+3]);
    }
    __syncthreads();
    if (q2 == 0) {
      const float* src = &sl2[cl2 * 16];
      float* op = out + ((size_t)(n * 256 + cl2) * 64) + g * 16;
      #pragma unroll
      for (int kq = 0; kq < 4; kq++) {
        const float4 iv = *(const float4*)&invden_l[kq * 4];
        float4 o;
        o.x = (acc2[kq*4+0] + src[kq*4+0]) * iv.x;
        o.y = (acc2[kq*4+1] + src[kq*4+1]) * iv.y;
        o.z = (acc2[kq*4+2] + src[kq*4+2]) * iv.z;
        o.w = (acc2[kq*4+3] + src[kq*4+3]) * iv.w;
        ((float4*)op)[kq] = o;
      }
    }
  }
  __syncthreads();   // pass-2 done; scratch16 free for topk histograms

  // ---- fused exact top-88 mean (per-wave radix select; supp in rsl) ----
  {
    uint32_t* hist_l = scratch16;
    const int k = w;               // wave w owns latent k
    uint32_t key[11];
    #pragma unroll
    for (int j = 0; j < 11; j++)
      key[j] = __float_as_uint(rsl[k * 704 + l + 64 * j]);  // supp>=0 -> monotone bits
    uint32_t* h = &hist_l[w * 256];
    uint32_t prefix = 0, remaining = TOPK_;
    #pragma unroll
    for (int b = 3; b >= 0; b--) {
      const int shift = b * 8;
      *(uint4*)&h[l * 4] = make_uint4(0u, 0u, 0u, 0u);
      uint32_t mhi = (b == 3) ? 0u : (0xFFFFFFFFu << (shift + 8));
      #pragma unroll
      for (int j = 0; j < 11; j++)
        if ((key[j] & mhi) == (prefix & mhi))
          atomicAdd(&h[(key[j] >> shift) & 255u], 1u);
      uint4 bn = *(uint4*)&h[l * 4];
      uint32_t T = bn.x + bn.y + bn.z + bn.w;
      uint32_t inc = T;
      #pragma unroll
      for (int off = 1; off < 64; off <<= 1) {
        uint32_t o = (uint32_t)__shfl_down((int)inc, off);
        if (l + off < 64) inc += o;
      }                              // inc = sum over lanes >= l
      uint32_t excl = inc - T;       // lanes > l
      uint32_t g3 = excl + bn.w, g2 = g3 + bn.z, g1 = g2 + bn.y, g0 = g1 + bn.x;
      uint32_t pk = 0u;
      if (g0 >= remaining && g1 < remaining) pk = ((uint32_t)(4*l+0) << 16) | (remaining - g1);
      if (g1 >= remaining && g2 < remaining) pk = ((uint32_t)(4*l+1) << 16) | (remaining - g2);
      if (g2 >= remaining && g3 < remaining) pk = ((uint32_t)(4*l+2) << 16) | (remaining - g3);
      if (g3 >= remaining && excl < remaining) pk = ((uint32_t)(4*l+3) << 16) | (remaining - excl);
      #pragma unroll
      for (int off = 32; off >= 1; off >>= 1) pk |= (uint32_t)__shfl_xor((int)pk, off);
      prefix |= ((pk >> 16) & 255u) << shift;
      remaining = pk & 0xFFFFu;
    }
    float tf = __uint_as_float(prefix);
    float sgt = 0.f; uint32_t cgt = 0u;
    #pragma unroll
    for (int j = 0; j < 11; j++)
      if (key[j] > prefix) { sgt += __uint_as_float(key[j]); cgt++; }
    #pragma unroll
    for (int off = 32; off >= 1; off >>= 1) {
      sgt += __shfl_xor(sgt, off);
      cgt += (uint32_t)__shfl_xor((int)cgt, off);
    }
    if (l == 0)
      presraw[s * 16 + k] = (sgt + (float)(TOPK_ - cgt) * tf) * (1.f / (float)TOPK_);
  }
}

// ---------------- kernel D: presence normalization ----------------
__global__ __launch_bounds__(64) void k_pres(const float* __restrict__ presraw,
                                             float* __restrict__ out) {
  const int n = blockIdx.x, t = threadIdx.x;
  float v = presraw[n * 64 + t];
  float ssum = v;
  #pragma unroll
  for (int off = 32; off >= 1; off >>= 1) ssum += __shfl_xor(ssum, off);
  out[1048576 + n * 64 + t] = v / fmaxf(ssum, EPS_);
}

extern "C" void kernel_launch(void* const* d_in, const int* in_sizes, int n_in,
                              void* d_out, int out_size, void* d_ws, size_t ws_size,
                              hipStream_t stream) {
  (void)in_sizes; (void)n_in; (void)out_size; (void)ws_size;
  const float* x  = (const float*)d_in[0];
  const float* lb = (const float*)d_in[1];
  float* out = (float*)d_out;
  float* ws = (float*)d_ws;
  float* lbn_ws     = ws;              // 16384 floats
  float* presraw_ws = ws + 20480;      // 4096

  k_norm_basis<<<64, 256, 0, stream>>>(lb, lbn_ws);
  k_route<<<256, 1024, 0, stream>>>(x, lbn_ws, out, presraw_ws);
  k_pres<<<64, 64, 0, stream>>>(presraw_ws, out);
}